// Round 5
// baseline (115.006 us; speedup 1.0000x reference)
//
#include <hip/hip_runtime.h>

#define BB 8
#define NN 4096
#define NPTS (2*BB*NN)            // 65536 packed points
#define PARTIAL_OFF (1 << 20)     // partial[] lives 1 MB into ws (past pk)

// Pre-pack both clouds as (x, y, z, 0.5*|p|^2) float4 -> ws.
// pk[0..32767] = src points, pk[32768..65535] = tgt points (b-major).
__global__ __launch_bounds__(256) void cd_pack(const float* __restrict__ src,
                                               const float* __restrict__ tgt,
                                               float4* __restrict__ pk) {
    int i = blockIdx.x * 256 + threadIdx.x;      // 0..65535
    const float* p = ((i >> 15) ? tgt : src) + 3 * (i & 32767);
    float x = p[0], y = p[1], z = p[2];
    pk[i] = make_float4(x, y, z, 0.5f * (x*x + y*y + z*z));
}

// Block = (dir, batch, 128-row tile), 1024 threads = 16 waves -> 2 blocks/CU
// = 8 waves/SIMD (full occupancy; TLP covers the SMEM drain latency).
// Wave w: rows rt*128 + (w&1)*64 + lane, j-slice (w>>1) of 512 targets.
// Targets are wave-uniform -> s_load into SGPRs; inner loop is pure VALU:
// acc = 0.5|t|^2 - <s,t> (3 v_fma, t comps as the single SGPR operand) + v_min.
// Row-constant 0.5|s|^2 is added after the slice-combine (min shift-invariant).
__global__ __launch_bounds__(1024) void cd_scan(const float4* __restrict__ pk,
                                                float* __restrict__ partial) {
    __shared__ float pm[8][128];     // [j-slice][row-in-block] partial mins
    __shared__ float bs[2];
    const int dir = blockIdx.z;                  // 0: src->tgt, 1: tgt->src
    const int b   = blockIdx.y;
    const int rt  = blockIdx.x;
    const int tid = threadIdx.x, lane = tid & 63, wave = tid >> 6;   // 0..15
    const int rowHalf = wave & 1;
    const int jsl     = wave >> 1;               // 0..7

    const float4* S = pk + (dir ? (size_t)BB*NN : 0) + (size_t)b*NN;
    const float4* T = pk + (dir ? 0 : (size_t)BB*NN) + (size_t)b*NN;

    // One source row per thread (coalesced dwordx4).
    const int rloc = rowHalf*64 + lane;          // 0..127
    float4 s = S[rt*128 + rloc];
    float nx = -s.x, ny = -s.y, nz = -s.z, q = s.w;

    // Wave-uniform target slice base -> scalar loads.
    const int jbase = __builtin_amdgcn_readfirstlane(jsl * 512);
    const float4* Tw = T + jbase;

    float m = 1.0e30f;
    for (int j = 0; j < 512; j += 8) {
        float4 t0 = Tw[j],   t1 = Tw[j+1], t2 = Tw[j+2], t3 = Tw[j+3];
        float4 t4 = Tw[j+4], t5 = Tw[j+5], t6 = Tw[j+6], t7 = Tw[j+7];
        float a0 = fmaf(nx, t0.x, fmaf(ny, t0.y, fmaf(nz, t0.z, t0.w)));
        float a1 = fmaf(nx, t1.x, fmaf(ny, t1.y, fmaf(nz, t1.z, t1.w)));
        float a2 = fmaf(nx, t2.x, fmaf(ny, t2.y, fmaf(nz, t2.z, t2.w)));
        float a3 = fmaf(nx, t3.x, fmaf(ny, t3.y, fmaf(nz, t3.z, t3.w)));
        float a4 = fmaf(nx, t4.x, fmaf(ny, t4.y, fmaf(nz, t4.z, t4.w)));
        float a5 = fmaf(nx, t5.x, fmaf(ny, t5.y, fmaf(nz, t5.z, t5.w)));
        float a6 = fmaf(nx, t6.x, fmaf(ny, t6.y, fmaf(nz, t6.z, t6.w)));
        float a7 = fmaf(nx, t7.x, fmaf(ny, t7.y, fmaf(nz, t7.z, t7.w)));
        float b0 = fminf(a0, a1), b1 = fminf(a2, a3);
        float b2 = fminf(a4, a5), b3 = fminf(a6, a7);
        m = fminf(m, fminf(fminf(b0, b1), fminf(b2, b3)));
    }

    pm[jsl][rloc] = m;
    __syncthreads();

    // Threads 0..127 each own row `tid` (wave0 -> 0..63, wave1 -> 64..127),
    // so the row's q is already in-register.
    float d = 0.0f;
    if (tid < 128) {
        float v = pm[0][tid];
#pragma unroll
        for (int sl = 1; sl < 8; ++sl) v = fminf(v, pm[sl][tid]);
        v = fmaxf(v + q, 0.0f);      // full d^2/2, clamp fp rounding negatives
        d = sqrtf(2.0f * v);
    }
#pragma unroll
    for (int o = 32; o > 0; o >>= 1) d += __shfl_down(d, o, 64);
    if (tid < 128 && lane == 0) bs[wave] = d;
    __syncthreads();
    if (tid == 0)
        partial[((size_t)dir*BB + b)*32 + rt] = bs[0] + bs[1];
}

__global__ __launch_bounds__(512) void cd_final(const float* __restrict__ partial,
                                                float* __restrict__ out) {
    __shared__ float ps[8];
    float v = partial[threadIdx.x];
#pragma unroll
    for (int o = 32; o > 0; o >>= 1) v += __shfl_down(v, o, 64);
    if ((threadIdx.x & 63) == 0) ps[threadIdx.x >> 6] = v;
    __syncthreads();
    if (threadIdx.x == 0) {
        float t = 0.0f;
#pragma unroll
        for (int w = 0; w < 8; ++w) t += ps[w];
        out[0] = t * (1.0f / (float)(BB * NN));   // mean(term1) + mean(term2)
    }
}

extern "C" void kernel_launch(void* const* d_in, const int* in_sizes, int n_in,
                              void* d_out, int out_size, void* d_ws, size_t ws_size,
                              hipStream_t stream) {
    const float* src = (const float*)d_in[0];
    const float* tgt = (const float*)d_in[1];
    float4* pk = (float4*)d_ws;                              // 1 MB
    float* partial = (float*)((char*)d_ws + PARTIAL_OFF);    // 512 floats
    float* out = (float*)d_out;

    cd_pack<<<NPTS / 256, 256, 0, stream>>>(src, tgt, pk);
    dim3 grid(NN / 128, BB, 2);                              // 32 x 8 x 2 = 512
    cd_scan<<<grid, 1024, 0, stream>>>(pk, partial);
    cd_final<<<1, 512, 0, stream>>>(partial, out);
}

// Round 6
// 90.171 us; speedup vs baseline: 1.2754x; 1.2754x over previous
//
#include <hip/hip_runtime.h>

#define BB 8
#define NN 4096
#define NPTS (2*BB*NN)            // 65536 packed points
#define PARTIAL_OFF (1 << 20)     // partial[] lives 1 MB into ws (past pk)
#define RPT 4                     // rows per thread
#define ROWS 256                  // rows per block (64 lanes * RPT)
#define WVS 16                    // waves per block
#define JSL (NN/WVS)              // 256 targets per wave-slice

// Pre-pack both clouds as (x, y, z, 0.5*|p|^2) float4 -> ws.
__global__ __launch_bounds__(256) void cd_pack(const float* __restrict__ src,
                                               const float* __restrict__ tgt,
                                               float4* __restrict__ pk) {
    int i = blockIdx.x * 256 + threadIdx.x;      // 0..65535
    const float* p = ((i >> 15) ? tgt : src) + 3 * (i & 32767);
    float x = p[0], y = p[1], z = p[2];
    pk[i] = make_float4(x, y, z, 0.5f * (x*x + y*y + z*z));
}

// Block = (dir, batch, 256-row tile); 256 blocks = 1/CU; 16 waves = 4/SIMD.
// Wave w scans j-slice w (256 targets) for all 256 rows (4 rows/thread).
// Targets are wave-uniform -> s_load to SGPRs. SMEM can't be software-
// pipelined (lgkmcnt(0) full drain), so the design maximizes VALU work per
// drain: 8 targets x 4 rows x 4 ops = 128 instrs (256 cyc) per 8-target
// batch; 4 waves/SIMD cover the drain latency via TLP.
__global__ __launch_bounds__(1024) void cd_scan(const float4* __restrict__ pk,
                                                float* __restrict__ partial) {
    __shared__ float pm[WVS][ROWS];  // 16 KB: per-slice row mins (q folded in)
    __shared__ float bs[WVS];
    const int dir = blockIdx.z;                  // 0: src->tgt, 1: tgt->src
    const int b   = blockIdx.y;
    const int rt  = blockIdx.x;
    const int tid = threadIdx.x, lane = tid & 63, wave = tid >> 6;   // 0..15

    const float4* S = pk + (dir ? (size_t)BB*NN : 0) + (size_t)b*NN;
    const float4* T = pk + (dir ? 0 : (size_t)BB*NN) + (size_t)b*NN;

    // 4 source rows per thread, coalesced (row = r*64 + lane).
    float nx[RPT], ny[RPT], nz[RPT], q[RPT];
#pragma unroll
    for (int r = 0; r < RPT; ++r) {
        float4 s = S[rt*ROWS + r*64 + lane];
        nx[r] = -s.x; ny[r] = -s.y; nz[r] = -s.z; q[r] = s.w;
    }

    // Wave-uniform target slice -> scalar loads.
    const int jbase = __builtin_amdgcn_readfirstlane(wave * JSL);
    const float4* Tw = T + jbase;

    float m[RPT];
#pragma unroll
    for (int r = 0; r < RPT; ++r) m[r] = 1.0e30f;

    for (int j = 0; j < JSL; j += 8) {
        float4 t0 = Tw[j],   t1 = Tw[j+1], t2 = Tw[j+2], t3 = Tw[j+3];
        float4 t4 = Tw[j+4], t5 = Tw[j+5], t6 = Tw[j+6], t7 = Tw[j+7];
#pragma unroll
        for (int r = 0; r < RPT; ++r) {
            float a0 = fmaf(nx[r], t0.x, fmaf(ny[r], t0.y, fmaf(nz[r], t0.z, t0.w)));
            float a1 = fmaf(nx[r], t1.x, fmaf(ny[r], t1.y, fmaf(nz[r], t1.z, t1.w)));
            float a2 = fmaf(nx[r], t2.x, fmaf(ny[r], t2.y, fmaf(nz[r], t2.z, t2.w)));
            float a3 = fmaf(nx[r], t3.x, fmaf(ny[r], t3.y, fmaf(nz[r], t3.z, t3.w)));
            float a4 = fmaf(nx[r], t4.x, fmaf(ny[r], t4.y, fmaf(nz[r], t4.z, t4.w)));
            float a5 = fmaf(nx[r], t5.x, fmaf(ny[r], t5.y, fmaf(nz[r], t5.z, t5.w)));
            float a6 = fmaf(nx[r], t6.x, fmaf(ny[r], t6.y, fmaf(nz[r], t6.z, t6.w)));
            float a7 = fmaf(nx[r], t7.x, fmaf(ny[r], t7.y, fmaf(nz[r], t7.z, t7.w)));
            float b0 = fminf(a0, a1), b1 = fminf(a2, a3);
            float b2 = fminf(a4, a5), b3 = fminf(a6, a7);
            m[r] = fminf(m[r], fminf(fminf(b0, b1), fminf(b2, b3)));
        }
    }

    // q folded in here: min_s(a_s) + q == min_s(a_s + q) per row.
#pragma unroll
    for (int r = 0; r < RPT; ++r)
        pm[wave][r*64 + lane] = m[r] + q[r];
    __syncthreads();

    // Threads 0..255 combine the 16 slice-partials for row `tid`.
    float d = 0.0f;
    if (tid < ROWS) {
        float v = pm[0][tid];
#pragma unroll
        for (int s = 1; s < WVS; ++s) v = fminf(v, pm[s][tid]);
        v = fmaxf(v, 0.0f);          // full d^2/2; clamp fp rounding negatives
        d = sqrtf(2.0f * v);
    }
#pragma unroll
    for (int o = 32; o > 0; o >>= 1) d += __shfl_down(d, o, 64);
    if (lane == 0) bs[wave] = d;
    __syncthreads();
    if (tid == 0) {
        float t = 0.0f;
#pragma unroll
        for (int w = 0; w < WVS; ++w) t += bs[w];
        partial[((size_t)dir*BB + b)*16 + rt] = t;
    }
}

__global__ __launch_bounds__(256) void cd_final(const float* __restrict__ partial,
                                                float* __restrict__ out) {
    __shared__ float ps[4];
    float v = partial[threadIdx.x];
#pragma unroll
    for (int o = 32; o > 0; o >>= 1) v += __shfl_down(v, o, 64);
    if ((threadIdx.x & 63) == 0) ps[threadIdx.x >> 6] = v;
    __syncthreads();
    if (threadIdx.x == 0) {
        out[0] = (ps[0] + ps[1] + ps[2] + ps[3]) * (1.0f / (float)(BB * NN));
    }
}

extern "C" void kernel_launch(void* const* d_in, const int* in_sizes, int n_in,
                              void* d_out, int out_size, void* d_ws, size_t ws_size,
                              hipStream_t stream) {
    const float* src = (const float*)d_in[0];
    const float* tgt = (const float*)d_in[1];
    float4* pk = (float4*)d_ws;                              // 1 MB
    float* partial = (float*)((char*)d_ws + PARTIAL_OFF);    // 256 floats
    float* out = (float*)d_out;

    cd_pack<<<NPTS / 256, 256, 0, stream>>>(src, tgt, pk);
    dim3 grid(NN / ROWS, BB, 2);                             // 16 x 8 x 2 = 256
    cd_scan<<<grid, 1024, 0, stream>>>(pk, partial);
    cd_final<<<1, 256, 0, stream>>>(partial, out);
}